// Round 10
// baseline (1604.964 us; speedup 1.0000x reference)
//
#include <hip/hip_runtime.h>
#include <cstdint>

#define S_LEN 2048
#define DM 4096
#define NQH 32
#define NKVH 8
#define HD 128

typedef __bf16 bf16x8 __attribute__((ext_vector_type(8)));
typedef float f32x4 __attribute__((ext_vector_type(4)));
typedef unsigned short u16;
typedef unsigned short u16x8 __attribute__((ext_vector_type(8)));
typedef unsigned int u32;

__device__ __forceinline__ float bf2f(u16 h) {
  union { u32 u; float f; } v; v.u = ((u32)h) << 16; return v.f;
}
__device__ __forceinline__ u16 f2bf(float f) {
  union { float f; u32 u; } v; v.f = f;
  u32 u = v.u;
  return (u16)((u + 0x7FFFu + ((u >> 16) & 1u)) >> 16);
}

// ---- staging helpers: 16 contiguous elements global -> LDS (2x ds_write_b128)
__device__ __forceinline__ void stage16(const float* __restrict__ g, u16* l) {
  const float4* gp = reinterpret_cast<const float4*>(g);
  float4 v0 = gp[0], v1 = gp[1], v2 = gp[2], v3 = gp[3];
  u16x8 a, b;
  a[0] = f2bf(v0.x); a[1] = f2bf(v0.y); a[2] = f2bf(v0.z); a[3] = f2bf(v0.w);
  a[4] = f2bf(v1.x); a[5] = f2bf(v1.y); a[6] = f2bf(v1.z); a[7] = f2bf(v1.w);
  b[0] = f2bf(v2.x); b[1] = f2bf(v2.y); b[2] = f2bf(v2.z); b[3] = f2bf(v2.w);
  b[4] = f2bf(v3.x); b[5] = f2bf(v3.y); b[6] = f2bf(v3.z); b[7] = f2bf(v3.w);
  *reinterpret_cast<u16x8*>(l) = a;
  *reinterpret_cast<u16x8*>(l + 8) = b;
}
__device__ __forceinline__ void stage16(const u16* __restrict__ g, u16* l) {
  *reinterpret_cast<u16x8*>(l) = *reinterpret_cast<const u16x8*>(g);
  *reinterpret_cast<u16x8*>(l + 8) = *reinterpret_cast<const u16x8*>(g + 8);
}

// output store: bf16 (intermediates) or f32 (final d_out)
__device__ __forceinline__ void stc(u16* p, float v) { *p = f2bf(v); }
__device__ __forceinline__ void stc(float* p, float v) { *p = v; }

// ---------------- RoPE table (llama3 scaling), fp64 ----------------
__global__ void rope_table_kernel(float* __restrict__ sin_t, float* __restrict__ cos_t) {
  int idx = blockIdx.x * blockDim.x + threadIdx.x;
  if (idx >= S_LEN * 64) return;
  int s = idx >> 6, i = idx & 63;
  const double PI = 3.14159265358979323846;
  double freq = pow(500000.0, -((double)i) / 64.0);
  double wavelen = 2.0 * PI / freq;
  double inv = (wavelen > 8192.0) ? freq / 32.0 : freq;
  if (!(wavelen < 2048.0) && !(wavelen > 8192.0)) {
    double smooth = (8192.0 / wavelen - 1.0) / 3.0;
    inv = (1.0 - smooth) * (freq / 32.0) + smooth * freq;
  }
  double ang = (double)s * inv;
  sin_t[idx] = (float)sin(ang);
  cos_t[idx] = (float)cos(ang);
}

// ---------------- RoPE apply in place on [B,H,S,128] bf16 ----------------
__global__ void rope_apply(u16* __restrict__ X, const float* __restrict__ sin_t,
                           const float* __restrict__ cos_t, float scale, int nrows) {
  int idx = blockIdx.x * blockDim.x + threadIdx.x;
  if (idx >= nrows * 64) return;
  int row = idx >> 6, i = idx & 63;
  int s = row & (S_LEN - 1);
  size_t base = (size_t)row * HD;
  float lo = bf2f(X[base + i]);
  float hi = bf2f(X[base + i + 64]);
  float sn = sin_t[s * 64 + i];
  float cs = cos_t[s * 64 + i];
  X[base + i] = f2bf((lo * cs - hi * sn) * scale);
  X[base + i + 64] = f2bf((hi * cs + lo * sn) * scale);
}

// ---------------- GEMM: C = A(MxK) * B(NxK)^T, f32 acc ----------------
// MODE 0: C[m*N+n]
// MODE 1: head-scatter  out[((b*H+h)*S + s)*128 + d]   (m=b*2048+s, n=h*128+d)
// MODE 2: v-transpose   out[((b*H+h)*128 + d)*S + s]
template <int MODE, typename TA, typename TB, typename TC>
__global__ __launch_bounds__(256, 2)
void gemm_bt(const TA* __restrict__ A, const TB* __restrict__ B,
             TC* __restrict__ C, int M, int N, int K, int H) {
  __shared__ u16 sA[128 * 32];
  __shared__ u16 sB[128 * 32];
  const int tid = threadIdx.x;
  const int lane = tid & 63;
  const int wv = tid >> 6;
  const int wr = wv >> 1, wc = wv & 1;
  const int bm = blockIdx.y * 128;
  const int bn = blockIdx.x * 128;
  const int fr = lane & 15, fq = lane >> 4;
  const int srow = tid >> 1;          // staging row 0..127
  const int shalf = (tid & 1) * 16;   // staging col offset

  f32x4 zero4 = {0.f, 0.f, 0.f, 0.f};
  f32x4 acc[4][4];
#pragma unroll
  for (int i = 0; i < 4; ++i)
#pragma unroll
    for (int j = 0; j < 4; ++j) acc[i][j] = zero4;

  for (int k0 = 0; k0 < K; k0 += 32) {
    __syncthreads();
    stage16(A + (size_t)(bm + srow) * K + k0 + shalf, sA + srow * 32 + shalf);
    stage16(B + (size_t)(bn + srow) * K + k0 + shalf, sB + srow * 32 + shalf);
    __syncthreads();
    bf16x8 af[4], bg[4];
#pragma unroll
    for (int i = 0; i < 4; ++i) {
      af[i] = *(const bf16x8*)(sA + (wr * 64 + i * 16 + fr) * 32 + fq * 8);
      bg[i] = *(const bf16x8*)(sB + (wc * 64 + i * 16 + fr) * 32 + fq * 8);
    }
#pragma unroll
    for (int i = 0; i < 4; ++i)
#pragma unroll
      for (int j = 0; j < 4; ++j)
        acc[i][j] = __builtin_amdgcn_mfma_f32_16x16x32_bf16(af[i], bg[j], acc[i][j], 0, 0, 0);
  }

#pragma unroll
  for (int i = 0; i < 4; ++i)
#pragma unroll
    for (int j = 0; j < 4; ++j)
#pragma unroll
      for (int r = 0; r < 4; ++r) {
        int m = bm + wr * 64 + i * 16 + fq * 4 + r;
        int n = bn + wc * 64 + j * 16 + fr;
        float v = acc[i][j][r];
        if (MODE == 0) {
          stc(C + (size_t)m * N + n, v);
        } else if (MODE == 1) {
          int b = m >> 11, s = m & 2047, hh = n >> 7, d = n & 127;
          stc(C + (((size_t)(b * H + hh)) * S_LEN + s) * HD + d, v);
        } else {
          int b = m >> 11, s = m & 2047, hh = n >> 7, d = n & 127;
          stc(C + (((size_t)(b * H + hh)) * HD + d) * S_LEN + s, v);
        }
      }
}

// ---------------- causal GQA flash attention ----------------
// Q [B,32,S,128], K [B,8,S,128], V transposed [B,8,128,S]; out [B*S, 4096] bf16.
// grid: (S/64, B*32), block 256. Wave w owns q rows [q0+16w, q0+16w+16).
__global__ __launch_bounds__(256, 2)
void attn_kernel(const u16* __restrict__ Q, const u16* __restrict__ K,
                 const u16* __restrict__ V, u16* __restrict__ O) {
  __shared__ u16 sK[64 * 128];   // [kv][d]
  __shared__ u16 sV[128 * 64];   // [d][kv]
  __shared__ u16 sP[4][16 * 64]; // per-wave P

  const int tid = threadIdx.x, lane = tid & 63, wv = tid >> 6;
  const int fr = lane & 15, fq = lane >> 4;
  const int q0 = blockIdx.x * 64;
  const int bh = blockIdx.y;
  const int b = bh >> 5, h = bh & 31;
  const int hkv = h >> 2;
  const u16* Qb = Q + (size_t)bh * S_LEN * HD;
  const u16* Kb = K + (size_t)(b * NKVH + hkv) * S_LEN * HD;
  const u16* Vb = V + (size_t)(b * NKVH + hkv) * HD * S_LEN;

  const int krow = tid >> 2, kcol = (tid & 3) * 32;  // K-tile staging
  const int vrow = tid >> 1, vcol = (tid & 1) * 32;  // V-tile staging

  // Q fragments in registers (scale already folded in)
  bf16x8 qf[4];
  {
    int qrow = q0 + wv * 16 + fr;
#pragma unroll
    for (int ks = 0; ks < 4; ++ks)
      qf[ks] = *(const bf16x8*)(Qb + (size_t)qrow * HD + ks * 32 + fq * 8);
  }

  f32x4 zero4 = {0.f, 0.f, 0.f, 0.f};
  f32x4 o[8];
#pragma unroll
  for (int dt = 0; dt < 8; ++dt) o[dt] = zero4;
  float m[4], l[4];
#pragma unroll
  for (int r = 0; r < 4; ++r) { m[r] = -3.0e38f; l[r] = 0.f; }

  const int ntiles = (q0 >> 6) + 1;
  for (int t = 0; t < ntiles; ++t) {
    const int s0 = t * 64;
    __syncthreads();
#pragma unroll
    for (int u = 0; u < 2; ++u)
      stage16(Kb + (size_t)(s0 + krow) * HD + kcol + u * 16, sK + krow * 128 + kcol + u * 16);
#pragma unroll
    for (int u = 0; u < 2; ++u)
      stage16(Vb + (size_t)vrow * S_LEN + s0 + vcol + u * 16, sV + vrow * 64 + vcol + u * 16);
    __syncthreads();

    // QK^T: sc[j] rows q=fq*4+r, cols kv=s0+j*16+fr
    f32x4 sc[4];
#pragma unroll
    for (int j = 0; j < 4; ++j) sc[j] = zero4;
#pragma unroll
    for (int j = 0; j < 4; ++j) {
#pragma unroll
      for (int ks = 0; ks < 4; ++ks) {
        bf16x8 kf = *(const bf16x8*)(sK + (j * 16 + fr) * 128 + ks * 32 + fq * 8);
        sc[j] = __builtin_amdgcn_mfma_f32_16x16x32_bf16(qf[ks], kf, sc[j], 0, 0, 0);
      }
    }

    if (t == ntiles - 1) {  // diagonal tile: causal mask
#pragma unroll
      for (int j = 0; j < 4; ++j)
#pragma unroll
        for (int r = 0; r < 4; ++r) {
          int kvp = s0 + j * 16 + fr;
          int qp = q0 + wv * 16 + fq * 4 + r;
          if (kvp > qp) sc[j][r] = -3.0e38f;
        }
    }

    // online softmax (row groups: 16 lanes sharing fq)
    float al[4];
#pragma unroll
    for (int r = 0; r < 4; ++r) {
      float v = fmaxf(fmaxf(sc[0][r], sc[1][r]), fmaxf(sc[2][r], sc[3][r]));
      v = fmaxf(v, __shfl_xor(v, 1, 64));
      v = fmaxf(v, __shfl_xor(v, 2, 64));
      v = fmaxf(v, __shfl_xor(v, 4, 64));
      v = fmaxf(v, __shfl_xor(v, 8, 64));
      float mn = fmaxf(m[r], v);
      al[r] = __expf(m[r] - mn);
      m[r] = mn;
    }
#pragma unroll
    for (int r = 0; r < 4; ++r) {
      float rs = 0.f;
      int prow = fq * 4 + r;
#pragma unroll
      for (int j = 0; j < 4; ++j) {
        float p = __expf(sc[j][r] - m[r]);
        rs += p;
        sP[wv][prow * 64 + j * 16 + fr] = f2bf(p);
      }
      rs += __shfl_xor(rs, 1, 64);
      rs += __shfl_xor(rs, 2, 64);
      rs += __shfl_xor(rs, 4, 64);
      rs += __shfl_xor(rs, 8, 64);
      l[r] = l[r] * al[r] + rs;
#pragma unroll
      for (int dt = 0; dt < 8; ++dt) o[dt][r] *= al[r];
    }

    // P as A-fragments (same-wave LDS write->read; compiler orders via lgkmcnt)
    bf16x8 pa[2];
#pragma unroll
    for (int ks = 0; ks < 2; ++ks)
      pa[ks] = *(const bf16x8*)(&sP[wv][fr * 64 + ks * 32 + fq * 8]);
    // PV: o rows q, cols d=dt*16+fr
#pragma unroll
    for (int dt = 0; dt < 8; ++dt) {
#pragma unroll
      for (int ks = 0; ks < 2; ++ks) {
        bf16x8 vf = *(const bf16x8*)(sV + (dt * 16 + fr) * 64 + ks * 32 + fq * 8);
        o[dt] = __builtin_amdgcn_mfma_f32_16x16x32_bf16(pa[ks], vf, o[dt], 0, 0, 0);
      }
    }
  }

  // epilogue: out[(b*S+q)*4096 + h*128 + d]
#pragma unroll
  for (int r = 0; r < 4; ++r) {
    int qp = q0 + wv * 16 + fq * 4 + r;
    float inv_l = 1.0f / l[r];
    size_t base = ((size_t)b * S_LEN + qp) * DM + h * HD;
#pragma unroll
    for (int dt = 0; dt < 8; ++dt)
      O[base + dt * 16 + fr] = f2bf(o[dt][r] * inv_l);
  }
}

extern "C" void kernel_launch(void* const* d_in, const int* in_sizes, int n_in,
                              void* d_out, int out_size, void* d_ws, size_t ws_size,
                              hipStream_t stream) {
  // Inputs f32 in declared dict order; OUTPUT IS FLOAT32 (reference returns
  // jnp.float32 — the harness label "(bf16, ...)" refers to threshold mode,
  // not the d_out read path).
  const float* x  = (const float*)d_in[0];
  const float* wq = (const float*)d_in[1];
  const float* wk = (const float*)d_in[2];
  const float* wv = (const float*)d_in[3];
  const float* wo = (const float*)d_in[4];

  char* ws = (char*)d_ws;
  size_t off = 0;
  auto alloc = [&](size_t bytes) {
    void* p = ws + off;
    off += (bytes + 255) & ~(size_t)255;
    return p;
  };

  const size_t nx  = (size_t)2 * S_LEN * DM;       // 16.8M elements
  const size_t nwk = (size_t)(NKVH * HD) * DM;     // 4.2M elements

  u16* qb  = (u16*)alloc(nx * 2);      // [B,32,S,128]   33.6 MB
  u16* kb  = (u16*)alloc(nwk * 2);     // [B,8,S,128]     8.4 MB
  u16* vtb = (u16*)alloc(nwk * 2);     // [B,8,128,S]     8.4 MB
  u16* aob = (u16*)alloc(nx * 2);      // [B*S, 4096]    33.6 MB
  float* sin_t = (float*)alloc((size_t)S_LEN * 64 * 4);
  float* cos_t = (float*)alloc((size_t)S_LEN * 64 * 4);

  rope_table_kernel<<<(S_LEN * 64 + 255) / 256, 256, 0, stream>>>(sin_t, cos_t);

  dim3 blk(256);
  gemm_bt<1, float, float, u16><<<dim3(DM / 128, 4096 / 128), blk, 0, stream>>>(x, wq, qb, 4096, DM, DM, NQH);
  gemm_bt<1, float, float, u16><<<dim3(1024 / 128, 4096 / 128), blk, 0, stream>>>(x, wk, kb, 4096, 1024, DM, NKVH);
  gemm_bt<2, float, float, u16><<<dim3(1024 / 128, 4096 / 128), blk, 0, stream>>>(x, wv, vtb, 4096, 1024, DM, NKVH);

  const float scale = 0.08838834764831845f;  // 1/sqrt(128), folded into Q
  int nrq = 2 * NQH * S_LEN, nrk = 2 * NKVH * S_LEN;
  rope_apply<<<((size_t)nrq * 64 + 255) / 256, 256, 0, stream>>>(qb, sin_t, cos_t, scale, nrq);
  rope_apply<<<((size_t)nrk * 64 + 255) / 256, 256, 0, stream>>>(kb, sin_t, cos_t, 1.0f, nrk);

  attn_kernel<<<dim3(S_LEN / 64, 2 * NQH), blk, 0, stream>>>(qb, kb, vtb, aob);

  gemm_bt<0, u16, float, float><<<dim3(DM / 128, 4096 / 128), blk, 0, stream>>>(aob, wo, (float*)d_out, 4096, DM, DM, 0);
}

// Round 12
// 852.225 us; speedup vs baseline: 1.8833x; 1.8833x over previous
//
#include <hip/hip_runtime.h>
#include <cstdint>

#define S_LEN 2048
#define DM 4096
#define NQH 32
#define NKVH 8
#define HD 128

typedef __bf16 bf16x8 __attribute__((ext_vector_type(8)));
typedef float f32x4 __attribute__((ext_vector_type(4)));
typedef unsigned short u16;
typedef unsigned short u16x8 __attribute__((ext_vector_type(8)));
typedef unsigned int u32;

__device__ __forceinline__ float bf2f(u16 h) {
  union { u32 u; float f; } v; v.u = ((u32)h) << 16; return v.f;
}
__device__ __forceinline__ u16 f2bf(float f) {
  union { float f; u32 u; } v; v.f = f;
  u32 u = v.u;
  return (u16)((u + 0x7FFFu + ((u >> 16) & 1u)) >> 16);
}

// global -> LDS direct DMA, 16B/lane. LDS dest = wave-uniform base + lane*16;
// global source is per-lane (bit-validated: rounds 1/2/4 agree bit-exactly).
__device__ __forceinline__ void gload16(const void* g, const void* l) {
  __builtin_amdgcn_global_load_lds(
      (const __attribute__((address_space(1))) u32*)(uintptr_t)g,
      (__attribute__((address_space(3))) u32*)(u32)(uintptr_t)l,
      16, 0, 0);
}

// ---- reg-staging helpers (fallback path): 16 elements global -> LDS
__device__ __forceinline__ void stage16(const float* __restrict__ g, u16* l) {
  const float4* gp = reinterpret_cast<const float4*>(g);
  float4 v0 = gp[0], v1 = gp[1], v2 = gp[2], v3 = gp[3];
  u16x8 a, b;
  a[0] = f2bf(v0.x); a[1] = f2bf(v0.y); a[2] = f2bf(v0.z); a[3] = f2bf(v0.w);
  a[4] = f2bf(v1.x); a[5] = f2bf(v1.y); a[6] = f2bf(v1.z); a[7] = f2bf(v1.w);
  b[0] = f2bf(v2.x); b[1] = f2bf(v2.y); b[2] = f2bf(v2.z); b[3] = f2bf(v2.w);
  b[4] = f2bf(v3.x); b[5] = f2bf(v3.y); b[6] = f2bf(v3.z); b[7] = f2bf(v3.w);
  *reinterpret_cast<u16x8*>(l) = a;
  *reinterpret_cast<u16x8*>(l + 8) = b;
}
__device__ __forceinline__ void stage16(const u16* __restrict__ g, u16* l) {
  *reinterpret_cast<u16x8*>(l) = *reinterpret_cast<const u16x8*>(g);
  *reinterpret_cast<u16x8*>(l + 8) = *reinterpret_cast<const u16x8*>(g + 8);
}

// output store: bf16 (intermediates) or f32 (final d_out)
__device__ __forceinline__ void stc(u16* p, float v) { *p = f2bf(v); }
__device__ __forceinline__ void stc(float* p, float v) { *p = v; }

// ---------------- f32 -> bf16 bulk convert ----------------
__global__ void cvt_f32_bf16(const float* __restrict__ in, u16* __restrict__ out, int n8) {
  int i = blockIdx.x * blockDim.x + threadIdx.x;
  if (i >= n8) return;
  const float4* gp = reinterpret_cast<const float4*>(in) + (size_t)i * 2;
  float4 a = gp[0], b = gp[1];
  u16x8 o;
  o[0] = f2bf(a.x); o[1] = f2bf(a.y); o[2] = f2bf(a.z); o[3] = f2bf(a.w);
  o[4] = f2bf(b.x); o[5] = f2bf(b.y); o[6] = f2bf(b.z); o[7] = f2bf(b.w);
  reinterpret_cast<u16x8*>(out)[i] = o;
}

// ---------------- RoPE table (llama3 scaling), fp64 ----------------
__global__ void rope_table_kernel(float* __restrict__ sin_t, float* __restrict__ cos_t) {
  int idx = blockIdx.x * blockDim.x + threadIdx.x;
  if (idx >= S_LEN * 64) return;
  int s = idx >> 6, i = idx & 63;
  const double PI = 3.14159265358979323846;
  double freq = pow(500000.0, -((double)i) / 64.0);
  double wavelen = 2.0 * PI / freq;
  double inv = (wavelen > 8192.0) ? freq / 32.0 : freq;
  if (!(wavelen < 2048.0) && !(wavelen > 8192.0)) {
    double smooth = (8192.0 / wavelen - 1.0) / 3.0;
    inv = (1.0 - smooth) * (freq / 32.0) + smooth * freq;
  }
  double ang = (double)s * inv;
  sin_t[idx] = (float)sin(ang);
  cos_t[idx] = (float)cos(ang);
}

// ---------------- RoPE apply in place on [B,H,S,128] bf16 ----------------
__global__ void rope_apply(u16* __restrict__ X, const float* __restrict__ sin_t,
                           const float* __restrict__ cos_t, float scale, int nrows) {
  int idx = blockIdx.x * blockDim.x + threadIdx.x;
  if (idx >= nrows * 64) return;
  int row = idx >> 6, i = idx & 63;
  int s = row & (S_LEN - 1);
  size_t base = (size_t)row * HD;
  float lo = bf2f(X[base + i]);
  float hi = bf2f(X[base + i + 64]);
  float sn = sin_t[s * 64 + i];
  float cs = cos_t[s * 64 + i];
  X[base + i] = f2bf((lo * cs - hi * sn) * scale);
  X[base + i + 64] = f2bf((hi * cs + lo * sn) * scale);
}

// ================= GEMM (bf16 inputs, gload16 staging, m97 structure) ========
// C = A(MxK) * B(NxK)^T, f32 acc.
// MODE 0: C[m*N+n]; MODE 1: head-scatter; MODE 2: v-transpose.
template <int MODE, typename TC>
__global__ __launch_bounds__(256, 2)
void gemm16(const u16* __restrict__ A, const u16* __restrict__ B,
            TC* __restrict__ C, int M, int N, int K, int H) {
  __shared__ u16 sA[128 * 32];
  __shared__ u16 sB[128 * 32];
  const int tid = threadIdx.x;
  const int lane = tid & 63;
  const int wv = tid >> 6;
  const int wr = wv >> 1, wc = wv & 1;
  const int bm = blockIdx.y * 128;
  const int bn = blockIdx.x * 128;
  const int fr = lane & 15, fq = lane >> 4;
  const int srow = lane >> 2;        // row within 16-row chunk
  const int scol = (lane & 3) * 8;   // element col

  f32x4 zero4 = {0.f, 0.f, 0.f, 0.f};
  f32x4 acc[4][4];
#pragma unroll
  for (int i = 0; i < 4; ++i)
#pragma unroll
    for (int j = 0; j < 4; ++j) acc[i][j] = zero4;

  for (int k0 = 0; k0 < K; k0 += 32) {
    __syncthreads();
#pragma unroll
    for (int j = 0; j < 2; ++j) {
      int c = j * 4 + wv;
      int row = c * 16 + srow;
      gload16(A + (size_t)(bm + row) * K + k0 + scol, sA + c * 512);
      gload16(B + (size_t)(bn + row) * K + k0 + scol, sB + c * 512);
    }
    __syncthreads();
    bf16x8 af[4], bg[4];
#pragma unroll
    for (int i = 0; i < 4; ++i) {
      af[i] = *(const bf16x8*)(sA + (wr * 64 + i * 16 + fr) * 32 + fq * 8);
      bg[i] = *(const bf16x8*)(sB + (wc * 64 + i * 16 + fr) * 32 + fq * 8);
    }
#pragma unroll
    for (int i = 0; i < 4; ++i)
#pragma unroll
      for (int j = 0; j < 4; ++j)
        acc[i][j] = __builtin_amdgcn_mfma_f32_16x16x32_bf16(af[i], bg[j], acc[i][j], 0, 0, 0);
  }

#pragma unroll
  for (int i = 0; i < 4; ++i)
#pragma unroll
    for (int j = 0; j < 4; ++j)
#pragma unroll
      for (int r = 0; r < 4; ++r) {
        int m = bm + wr * 64 + i * 16 + fq * 4 + r;
        int n = bn + wc * 64 + j * 16 + fr;
        float v = acc[i][j][r];
        if (MODE == 0) {
          stc(C + (size_t)m * N + n, v);
        } else if (MODE == 1) {
          int b = m >> 11, s = m & 2047, hh = n >> 7, d = n & 127;
          stc(C + (((size_t)(b * H + hh)) * S_LEN + s) * HD + d, v);
        } else {
          int b = m >> 11, s = m & 2047, hh = n >> 7, d = n & 127;
          stc(C + (((size_t)(b * H + hh)) * HD + d) * S_LEN + s, v);
        }
      }
}

// ================= GEMM fallback (reg-staged; round-10, templated A/B) =======
template <int MODE, typename TA, typename TB, typename TC>
__global__ __launch_bounds__(256, 2)
void gemm_bt(const TA* __restrict__ A, const TB* __restrict__ B,
             TC* __restrict__ C, int M, int N, int K, int H) {
  __shared__ u16 sA[128 * 32];
  __shared__ u16 sB[128 * 32];
  const int tid = threadIdx.x;
  const int lane = tid & 63;
  const int wv = tid >> 6;
  const int wr = wv >> 1, wc = wv & 1;
  const int bm = blockIdx.y * 128;
  const int bn = blockIdx.x * 128;
  const int fr = lane & 15, fq = lane >> 4;
  const int srow = tid >> 1;
  const int shalf = (tid & 1) * 16;

  f32x4 zero4 = {0.f, 0.f, 0.f, 0.f};
  f32x4 acc[4][4];
#pragma unroll
  for (int i = 0; i < 4; ++i)
#pragma unroll
    for (int j = 0; j < 4; ++j) acc[i][j] = zero4;

  for (int k0 = 0; k0 < K; k0 += 32) {
    __syncthreads();
    stage16(A + (size_t)(bm + srow) * K + k0 + shalf, sA + srow * 32 + shalf);
    stage16(B + (size_t)(bn + srow) * K + k0 + shalf, sB + srow * 32 + shalf);
    __syncthreads();
    bf16x8 af[4], bg[4];
#pragma unroll
    for (int i = 0; i < 4; ++i) {
      af[i] = *(const bf16x8*)(sA + (wr * 64 + i * 16 + fr) * 32 + fq * 8);
      bg[i] = *(const bf16x8*)(sB + (wc * 64 + i * 16 + fr) * 32 + fq * 8);
    }
#pragma unroll
    for (int i = 0; i < 4; ++i)
#pragma unroll
      for (int j = 0; j < 4; ++j)
        acc[i][j] = __builtin_amdgcn_mfma_f32_16x16x32_bf16(af[i], bg[j], acc[i][j], 0, 0, 0);
  }

#pragma unroll
  for (int i = 0; i < 4; ++i)
#pragma unroll
    for (int j = 0; j < 4; ++j)
#pragma unroll
      for (int r = 0; r < 4; ++r) {
        int m = bm + wr * 64 + i * 16 + fq * 4 + r;
        int n = bn + wc * 64 + j * 16 + fr;
        float v = acc[i][j][r];
        if (MODE == 0) {
          stc(C + (size_t)m * N + n, v);
        } else if (MODE == 1) {
          int b = m >> 11, s = m & 2047, hh = n >> 7, d = n & 127;
          stc(C + (((size_t)(b * H + hh)) * S_LEN + s) * HD + d, v);
        } else {
          int b = m >> 11, s = m & 2047, hh = n >> 7, d = n & 127;
          stc(C + (((size_t)(b * H + hh)) * HD + d) * S_LEN + s, v);
        }
      }
}

// ================= causal GQA flash attention (swizzled LDS) =================
// Q [B,32,S,128], K [B,8,S,128], V^T [B,8,128,S]; out [B*S,4096] bf16.
// grid (S/64, B*32), block 256. XOR swizzle: granule ^= (row&7) on K/V/P —
// staged via gload16 with pre-swizzled GLOBAL source (rule 21 pattern,
// bit-validated in round 1).
__global__ __launch_bounds__(256, 4)
void attn_kernel(const u16* __restrict__ Q, const u16* __restrict__ K,
                 const u16* __restrict__ V, u16* __restrict__ O) {
  __shared__ u16 sK[64 * 128];   // [kv][d], swizzled
  __shared__ u16 sV[128 * 64];   // [d][kv], swizzled
  __shared__ u16 sP[4][16 * 64]; // per-wave P, swizzled

  const int tid = threadIdx.x, lane = tid & 63, wv = tid >> 6;
  const int fr = lane & 15, fq = lane >> 4;
  const int q0 = blockIdx.x * 64;
  const int bh = blockIdx.y;
  const int b = bh >> 5, h = bh & 31;
  const int hkv = h >> 2;
  const u16* Qb = Q + (size_t)bh * S_LEN * HD;
  const u16* Kb = K + (size_t)(b * NKVH + hkv) * S_LEN * HD;
  const u16* Vb = V + (size_t)(b * NKVH + hkv) * HD * S_LEN;

  // Q fragments in registers (scale folded in)
  bf16x8 qf[4];
  {
    int qrow = q0 + wv * 16 + fr;
#pragma unroll
    for (int ks = 0; ks < 4; ++ks)
      qf[ks] = *(const bf16x8*)(Qb + (size_t)qrow * HD + ks * 32 + fq * 8);
  }

  f32x4 zero4 = {0.f, 0.f, 0.f, 0.f};
  f32x4 o[8];
#pragma unroll
  for (int dt = 0; dt < 8; ++dt) o[dt] = zero4;
  float m[4], l[4];
#pragma unroll
  for (int r = 0; r < 4; ++r) { m[r] = -3.0e38f; l[r] = 0.f; }

  const int ntiles = (q0 >> 6) + 1;
  for (int t = 0; t < ntiles; ++t) {
    const int s0 = t * 64;
    __syncthreads();
    // stage K (16 chunks) + V (16 chunks): linear LDS dest, swizzled source
#pragma unroll
    for (int j = 0; j < 4; ++j) {
      int c = j * 4 + wv;
      {
        int row = c * 4 + (lane >> 4);
        int e = ((lane & 15) ^ (row & 7)) * 8;
        gload16(Kb + (size_t)(s0 + row) * HD + e, sK + c * 512);
      }
      {
        int row = c * 8 + (lane >> 3);
        int e = ((lane & 7) ^ (row & 7)) * 8;
        gload16(Vb + (size_t)row * S_LEN + s0 + e, sV + c * 512);
      }
    }
    __syncthreads();

    // QK^T: sc[j] rows q=fq*4+r, cols kv=s0+j*16+fr
    f32x4 sc[4];
#pragma unroll
    for (int j = 0; j < 4; ++j) sc[j] = zero4;
#pragma unroll
    for (int j = 0; j < 4; ++j) {
#pragma unroll
      for (int ks = 0; ks < 4; ++ks) {
        int row = j * 16 + fr;
        int e = (ks * 32 + fq * 8) ^ ((row & 7) << 3);
        bf16x8 kf = *(const bf16x8*)(sK + row * 128 + e);
        sc[j] = __builtin_amdgcn_mfma_f32_16x16x32_bf16(qf[ks], kf, sc[j], 0, 0, 0);
      }
    }

    if (t == ntiles - 1) {  // diagonal tile: causal mask
#pragma unroll
      for (int j = 0; j < 4; ++j)
#pragma unroll
        for (int r = 0; r < 4; ++r) {
          int kvp = s0 + j * 16 + fr;
          int qp = q0 + wv * 16 + fq * 4 + r;
          if (kvp > qp) sc[j][r] = -3.0e38f;
        }
    }

    // online softmax (row groups: 16 lanes sharing fq)
    float al[4];
#pragma unroll
    for (int r = 0; r < 4; ++r) {
      float v = fmaxf(fmaxf(sc[0][r], sc[1][r]), fmaxf(sc[2][r], sc[3][r]));
      v = fmaxf(v, __shfl_xor(v, 1, 64));
      v = fmaxf(v, __shfl_xor(v, 2, 64));
      v = fmaxf(v, __shfl_xor(v, 4, 64));
      v = fmaxf(v, __shfl_xor(v, 8, 64));
      float mn = fmaxf(m[r], v);
      al[r] = __expf(m[r] - mn);
      m[r] = mn;
    }
#pragma unroll
    for (int r = 0; r < 4; ++r) {
      float rs = 0.f;
      int prow = fq * 4 + r;
#pragma unroll
      for (int j = 0; j < 4; ++j) {
        float p = __expf(sc[j][r] - m[r]);
        rs += p;
        int e = (j * 16 + fr) ^ ((prow & 7) << 3);
        sP[wv][prow * 64 + e] = f2bf(p);
      }
      rs += __shfl_xor(rs, 1, 64);
      rs += __shfl_xor(rs, 2, 64);
      rs += __shfl_xor(rs, 4, 64);
      rs += __shfl_xor(rs, 8, 64);
      l[r] = l[r] * al[r] + rs;
#pragma unroll
      for (int dt = 0; dt < 8; ++dt) o[dt][r] *= al[r];
    }

    // P as A-fragments (same-wave LDS write->read)
    bf16x8 pa[2];
#pragma unroll
    for (int ks = 0; ks < 2; ++ks) {
      int e = (ks * 32 + fq * 8) ^ ((fr & 7) << 3);
      pa[ks] = *(const bf16x8*)(&sP[wv][fr * 64 + e]);
    }
    // PV: o rows q, cols d=dt*16+fr
#pragma unroll
    for (int dt = 0; dt < 8; ++dt) {
#pragma unroll
      for (int ks = 0; ks < 2; ++ks) {
        int row = dt * 16 + fr;
        int e = (ks * 32 + fq * 8) ^ ((row & 7) << 3);
        bf16x8 vf = *(const bf16x8*)(sV + row * 64 + e);
        o[dt] = __builtin_amdgcn_mfma_f32_16x16x32_bf16(pa[ks], vf, o[dt], 0, 0, 0);
      }
    }
  }

  // epilogue: out[(b*S+q)*4096 + h*128 + d]
#pragma unroll
  for (int r = 0; r < 4; ++r) {
    int qp = q0 + wv * 16 + fq * 4 + r;
    float inv_l = 1.0f / l[r];
    size_t base = ((size_t)b * S_LEN + qp) * DM + h * HD;
#pragma unroll
    for (int dt = 0; dt < 8; ++dt)
      O[base + dt * 16 + fr] = f2bf(o[dt][r] * inv_l);
  }
}

extern "C" void kernel_launch(void* const* d_in, const int* in_sizes, int n_in,
                              void* d_out, int out_size, void* d_ws, size_t ws_size,
                              hipStream_t stream) {
  const float* x  = (const float*)d_in[0];
  const float* wq = (const float*)d_in[1];
  const float* wk = (const float*)d_in[2];
  const float* wv = (const float*)d_in[3];
  const float* wo = (const float*)d_in[4];

  char* ws = (char*)d_ws;
  size_t off = 0;
  auto alloc = [&](size_t bytes) {
    void* p = ws + off;
    off += (bytes + 255) & ~(size_t)255;
    return p;
  };

  const size_t nx  = (size_t)2 * S_LEN * DM;       // 16.78M elements
  const size_t nwq = (size_t)DM * DM;              // 16.78M
  const size_t nwk = (size_t)(NKVH * HD) * DM;     // 4.19M

  const float scale = 0.08838834764831845f;  // 1/sqrt(128), folded into Q
  const int nrq = 2 * NQH * S_LEN, nrk = 2 * NKVH * S_LEN;
  dim3 blk(256);

  if (ws_size >= ((size_t)180 << 20)) {
    // -------- fast path: one-time bf16 conversion + gload16 GEMMs --------
    u16* xb  = (u16*)alloc(nx * 2);   // also reused as aob after x dies
    u16* wqb = (u16*)alloc(nwq * 2);
    u16* wkb = (u16*)alloc(nwk * 2);
    u16* wvb = (u16*)alloc(nwk * 2);
    u16* wob = (u16*)alloc(nwq * 2);
    u16* qb  = (u16*)alloc(nx * 2);
    u16* kb  = (u16*)alloc(nwk * 2);
    u16* vtb = (u16*)alloc(nwk * 2);
    float* sin_t = (float*)alloc((size_t)S_LEN * 64 * 4);
    float* cos_t = (float*)alloc((size_t)S_LEN * 64 * 4);
    u16* aob = xb;  // alias: x (bf16) dead after the three projections

    auto cvt = [&](const float* in, u16* outb, size_t n) {
      int n8 = (int)(n / 8);
      cvt_f32_bf16<<<(n8 + 255) / 256, 256, 0, stream>>>(in, outb, n8);
    };
    cvt(x, xb, nx);
    cvt(wq, wqb, nwq);
    cvt(wk, wkb, nwk);
    cvt(wv, wvb, nwk);
    cvt(wo, wob, nwq);

    rope_table_kernel<<<(S_LEN * 64 + 255) / 256, 256, 0, stream>>>(sin_t, cos_t);

    gemm16<1, u16><<<dim3(32, 32), blk, 0, stream>>>(xb, wqb, qb, 4096, DM, DM, NQH);
    gemm16<1, u16><<<dim3(8, 32), blk, 0, stream>>>(xb, wkb, kb, 4096, 1024, DM, NKVH);
    gemm16<2, u16><<<dim3(8, 32), blk, 0, stream>>>(xb, wvb, vtb, 4096, 1024, DM, NKVH);

    rope_apply<<<((size_t)nrq * 64 + 255) / 256, 256, 0, stream>>>(qb, sin_t, cos_t, scale, nrq);
    rope_apply<<<((size_t)nrk * 64 + 255) / 256, 256, 0, stream>>>(kb, sin_t, cos_t, 1.0f, nrk);

    attn_kernel<<<dim3(32, 64), blk, 0, stream>>>(qb, kb, vtb, aob);

    gemm16<0, float><<<dim3(32, 32), blk, 0, stream>>>(aob, wob, (float*)d_out, 4096, DM, DM, 0);
  } else {
    // -------- fallback: proven round-10 path (f32 reg-staged GEMMs) --------
    u16* qb  = (u16*)alloc(nx * 2);
    u16* kb  = (u16*)alloc(nwk * 2);
    u16* vtb = (u16*)alloc(nwk * 2);
    u16* aob = (u16*)alloc(nx * 2);
    float* sin_t = (float*)alloc((size_t)S_LEN * 64 * 4);
    float* cos_t = (float*)alloc((size_t)S_LEN * 64 * 4);

    rope_table_kernel<<<(S_LEN * 64 + 255) / 256, 256, 0, stream>>>(sin_t, cos_t);

    gemm_bt<1, float, float, u16><<<dim3(32, 32), blk, 0, stream>>>(x, wq, qb, 4096, DM, DM, NQH);
    gemm_bt<1, float, float, u16><<<dim3(8, 32), blk, 0, stream>>>(x, wk, kb, 4096, 1024, DM, NKVH);
    gemm_bt<2, float, float, u16><<<dim3(8, 32), blk, 0, stream>>>(x, wv, vtb, 4096, 1024, DM, NKVH);

    rope_apply<<<((size_t)nrq * 64 + 255) / 256, 256, 0, stream>>>(qb, sin_t, cos_t, scale, nrq);
    rope_apply<<<((size_t)nrk * 64 + 255) / 256, 256, 0, stream>>>(kb, sin_t, cos_t, 1.0f, nrk);

    attn_kernel<<<dim3(32, 64), blk, 0, stream>>>(qb, kb, vtb, aob);

    gemm_bt<0, u16, float, float><<<dim3(32, 32), blk, 0, stream>>>(aob, wo, (float*)d_out, 4096, DM, DM, 0);
  }
}

// Round 13
// 799.377 us; speedup vs baseline: 2.0078x; 1.0661x over previous
//
#include <hip/hip_runtime.h>
#include <cstdint>

#define S_LEN 2048
#define DM 4096
#define NQH 32
#define NKVH 8
#define HD 128

typedef __bf16 bf16x8 __attribute__((ext_vector_type(8)));
typedef float f32x4 __attribute__((ext_vector_type(4)));
typedef unsigned short u16;
typedef unsigned short u16x8 __attribute__((ext_vector_type(8)));
typedef unsigned int u32;

__device__ __forceinline__ float bf2f(u16 h) {
  union { u32 u; float f; } v; v.u = ((u32)h) << 16; return v.f;
}
__device__ __forceinline__ u16 f2bf(float f) {
  union { float f; u32 u; } v; v.f = f;
  u32 u = v.u;
  return (u16)((u + 0x7FFFu + ((u >> 16) & 1u)) >> 16);
}

// global -> LDS direct DMA, 16B/lane. LDS dest = wave-uniform base + lane*16;
// global source is per-lane (bit-validated vs reg-staged path).
__device__ __forceinline__ void gload16(const void* g, const void* l) {
  __builtin_amdgcn_global_load_lds(
      (const __attribute__((address_space(1))) u32*)(uintptr_t)g,
      (__attribute__((address_space(3))) u32*)(u32)(uintptr_t)l,
      16, 0, 0);
}

// ---- reg-staging helpers (fallback path): 16 elements global -> LDS
__device__ __forceinline__ void stage16(const float* __restrict__ g, u16* l) {
  const float4* gp = reinterpret_cast<const float4*>(g);
  float4 v0 = gp[0], v1 = gp[1], v2 = gp[2], v3 = gp[3];
  u16x8 a, b;
  a[0] = f2bf(v0.x); a[1] = f2bf(v0.y); a[2] = f2bf(v0.z); a[3] = f2bf(v0.w);
  a[4] = f2bf(v1.x); a[5] = f2bf(v1.y); a[6] = f2bf(v1.z); a[7] = f2bf(v1.w);
  b[0] = f2bf(v2.x); b[1] = f2bf(v2.y); b[2] = f2bf(v2.z); b[3] = f2bf(v2.w);
  b[4] = f2bf(v3.x); b[5] = f2bf(v3.y); b[6] = f2bf(v3.z); b[7] = f2bf(v3.w);
  *reinterpret_cast<u16x8*>(l) = a;
  *reinterpret_cast<u16x8*>(l + 8) = b;
}
__device__ __forceinline__ void stage16(const u16* __restrict__ g, u16* l) {
  *reinterpret_cast<u16x8*>(l) = *reinterpret_cast<const u16x8*>(g);
  *reinterpret_cast<u16x8*>(l + 8) = *reinterpret_cast<const u16x8*>(g + 8);
}

// output store: bf16 (intermediates) or f32 (final d_out)
__device__ __forceinline__ void stc(u16* p, float v) { *p = f2bf(v); }
__device__ __forceinline__ void stc(float* p, float v) { *p = v; }

// ---------------- f32 -> bf16 bulk convert ----------------
__global__ void cvt_f32_bf16(const float* __restrict__ in, u16* __restrict__ out, int n8) {
  int i = blockIdx.x * blockDim.x + threadIdx.x;
  if (i >= n8) return;
  const float4* gp = reinterpret_cast<const float4*>(in) + (size_t)i * 2;
  float4 a = gp[0], b = gp[1];
  u16x8 o;
  o[0] = f2bf(a.x); o[1] = f2bf(a.y); o[2] = f2bf(a.z); o[3] = f2bf(a.w);
  o[4] = f2bf(b.x); o[5] = f2bf(b.y); o[6] = f2bf(b.z); o[7] = f2bf(b.w);
  reinterpret_cast<u16x8*>(out)[i] = o;
}

// ---------------- RoPE table (llama3 scaling), fp64 ----------------
__global__ void rope_table_kernel(float* __restrict__ sin_t, float* __restrict__ cos_t) {
  int idx = blockIdx.x * blockDim.x + threadIdx.x;
  if (idx >= S_LEN * 64) return;
  int s = idx >> 6, i = idx & 63;
  const double PI = 3.14159265358979323846;
  double freq = pow(500000.0, -((double)i) / 64.0);
  double wavelen = 2.0 * PI / freq;
  double inv = (wavelen > 8192.0) ? freq / 32.0 : freq;
  if (!(wavelen < 2048.0) && !(wavelen > 8192.0)) {
    double smooth = (8192.0 / wavelen - 1.0) / 3.0;
    inv = (1.0 - smooth) * (freq / 32.0) + smooth * freq;
  }
  double ang = (double)s * inv;
  sin_t[idx] = (float)sin(ang);
  cos_t[idx] = (float)cos(ang);
}

// ---------------- RoPE apply in place on [B,H,S,128] bf16 ----------------
__global__ void rope_apply(u16* __restrict__ X, const float* __restrict__ sin_t,
                           const float* __restrict__ cos_t, float scale, int nrows) {
  int idx = blockIdx.x * blockDim.x + threadIdx.x;
  if (idx >= nrows * 64) return;
  int row = idx >> 6, i = idx & 63;
  int s = row & (S_LEN - 1);
  size_t base = (size_t)row * HD;
  float lo = bf2f(X[base + i]);
  float hi = bf2f(X[base + i + 64]);
  float sn = sin_t[s * 64 + i];
  float cs = cos_t[s * 64 + i];
  X[base + i] = f2bf((lo * cs - hi * sn) * scale);
  X[base + i + 64] = f2bf((hi * cs + lo * sn) * scale);
}

// ================= GEMM (bf16 inputs, gload16 staging, m97 structure) ========
// C = A(MxK) * B(NxK)^T, f32 acc.
// MODE 0: C[m*N+n]; MODE 1: head-scatter; MODE 2: v-transpose.
template <int MODE, typename TC>
__global__ __launch_bounds__(256, 2)
void gemm16(const u16* __restrict__ A, const u16* __restrict__ B,
            TC* __restrict__ C, int M, int N, int K, int H) {
  __shared__ u16 sA[128 * 32];
  __shared__ u16 sB[128 * 32];
  const int tid = threadIdx.x;
  const int lane = tid & 63;
  const int wv = tid >> 6;
  const int wr = wv >> 1, wc = wv & 1;
  const int bm = blockIdx.y * 128;
  const int bn = blockIdx.x * 128;
  const int fr = lane & 15, fq = lane >> 4;
  const int srow = lane >> 2;        // row within 16-row chunk
  const int scol = (lane & 3) * 8;   // element col

  f32x4 zero4 = {0.f, 0.f, 0.f, 0.f};
  f32x4 acc[4][4];
#pragma unroll
  for (int i = 0; i < 4; ++i)
#pragma unroll
    for (int j = 0; j < 4; ++j) acc[i][j] = zero4;

  for (int k0 = 0; k0 < K; k0 += 32) {
    __syncthreads();
#pragma unroll
    for (int j = 0; j < 2; ++j) {
      int c = j * 4 + wv;
      int row = c * 16 + srow;
      gload16(A + (size_t)(bm + row) * K + k0 + scol, sA + c * 512);
      gload16(B + (size_t)(bn + row) * K + k0 + scol, sB + c * 512);
    }
    __syncthreads();
    bf16x8 af[4], bg[4];
#pragma unroll
    for (int i = 0; i < 4; ++i) {
      af[i] = *(const bf16x8*)(sA + (wr * 64 + i * 16 + fr) * 32 + fq * 8);
      bg[i] = *(const bf16x8*)(sB + (wc * 64 + i * 16 + fr) * 32 + fq * 8);
    }
#pragma unroll
    for (int i = 0; i < 4; ++i)
#pragma unroll
      for (int j = 0; j < 4; ++j)
        acc[i][j] = __builtin_amdgcn_mfma_f32_16x16x32_bf16(af[i], bg[j], acc[i][j], 0, 0, 0);
  }

#pragma unroll
  for (int i = 0; i < 4; ++i)
#pragma unroll
    for (int j = 0; j < 4; ++j)
#pragma unroll
      for (int r = 0; r < 4; ++r) {
        int m = bm + wr * 64 + i * 16 + fq * 4 + r;
        int n = bn + wc * 64 + j * 16 + fr;
        float v = acc[i][j][r];
        if (MODE == 0) {
          stc(C + (size_t)m * N + n, v);
        } else if (MODE == 1) {
          int b = m >> 11, s = m & 2047, hh = n >> 7, d = n & 127;
          stc(C + (((size_t)(b * H + hh)) * S_LEN + s) * HD + d, v);
        } else {
          int b = m >> 11, s = m & 2047, hh = n >> 7, d = n & 127;
          stc(C + (((size_t)(b * H + hh)) * HD + d) * S_LEN + s, v);
        }
      }
}

// ================= GEMM fallback (reg-staged; round-10, templated A/B) =======
template <int MODE, typename TA, typename TB, typename TC>
__global__ __launch_bounds__(256, 2)
void gemm_bt(const TA* __restrict__ A, const TB* __restrict__ B,
             TC* __restrict__ C, int M, int N, int K, int H) {
  __shared__ u16 sA[128 * 32];
  __shared__ u16 sB[128 * 32];
  const int tid = threadIdx.x;
  const int lane = tid & 63;
  const int wv = tid >> 6;
  const int wr = wv >> 1, wc = wv & 1;
  const int bm = blockIdx.y * 128;
  const int bn = blockIdx.x * 128;
  const int fr = lane & 15, fq = lane >> 4;
  const int srow = tid >> 1;
  const int shalf = (tid & 1) * 16;

  f32x4 zero4 = {0.f, 0.f, 0.f, 0.f};
  f32x4 acc[4][4];
#pragma unroll
  for (int i = 0; i < 4; ++i)
#pragma unroll
    for (int j = 0; j < 4; ++j) acc[i][j] = zero4;

  for (int k0 = 0; k0 < K; k0 += 32) {
    __syncthreads();
    stage16(A + (size_t)(bm + srow) * K + k0 + shalf, sA + srow * 32 + shalf);
    stage16(B + (size_t)(bn + srow) * K + k0 + shalf, sB + srow * 32 + shalf);
    __syncthreads();
    bf16x8 af[4], bg[4];
#pragma unroll
    for (int i = 0; i < 4; ++i) {
      af[i] = *(const bf16x8*)(sA + (wr * 64 + i * 16 + fr) * 32 + fq * 8);
      bg[i] = *(const bf16x8*)(sB + (wc * 64 + i * 16 + fr) * 32 + fq * 8);
    }
#pragma unroll
    for (int i = 0; i < 4; ++i)
#pragma unroll
      for (int j = 0; j < 4; ++j)
        acc[i][j] = __builtin_amdgcn_mfma_f32_16x16x32_bf16(af[i], bg[j], acc[i][j], 0, 0, 0);
  }

#pragma unroll
  for (int i = 0; i < 4; ++i)
#pragma unroll
    for (int j = 0; j < 4; ++j)
#pragma unroll
      for (int r = 0; r < 4; ++r) {
        int m = bm + wr * 64 + i * 16 + fq * 4 + r;
        int n = bn + wc * 64 + j * 16 + fr;
        float v = acc[i][j][r];
        if (MODE == 0) {
          stc(C + (size_t)m * N + n, v);
        } else if (MODE == 1) {
          int b = m >> 11, s = m & 2047, hh = n >> 7, d = n & 127;
          stc(C + (((size_t)(b * H + hh)) * S_LEN + s) * HD + d, v);
        } else {
          int b = m >> 11, s = m & 2047, hh = n >> 7, d = n & 127;
          stc(C + (((size_t)(b * H + hh)) * HD + d) * S_LEN + s, v);
        }
      }
}

// ================= causal GQA flash attention (QBLK=128, swizzled LDS) =======
// Q [B,32,S,128], K [B,8,S,128], V^T [B,8,128,S]; out [B*S,4096] bf16.
// grid (S/128, B*32), block 256. Wave owns 32 q-rows (two 16-row fragments).
// XOR swizzle granule ^= (row&7) on K/V/P; staged via gload16 with
// pre-swizzled GLOBAL source (both-sides pattern, bit-validated round 1).
__global__ __launch_bounds__(256, 2)
void attn_kernel(const u16* __restrict__ Q, const u16* __restrict__ K,
                 const u16* __restrict__ V, u16* __restrict__ O) {
  __shared__ u16 sK[64 * 128];   // [kv][d], swizzled
  __shared__ u16 sV[128 * 64];   // [d][kv], swizzled
  __shared__ u16 sP[4][32 * 64]; // per-wave P (32 rows), swizzled

  const int tid = threadIdx.x, lane = tid & 63, wv = tid >> 6;
  const int fr = lane & 15, fq = lane >> 4;
  const int q0 = blockIdx.x * 128;
  const int bh = blockIdx.y;
  const int b = bh >> 5, h = bh & 31;
  const int hkv = h >> 2;
  const u16* Qb = Q + (size_t)bh * S_LEN * HD;
  const u16* Kb = K + (size_t)(b * NKVH + hkv) * S_LEN * HD;
  const u16* Vb = V + (size_t)(b * NKVH + hkv) * HD * S_LEN;

  // Q fragments (scale folded in): rows q0 + wv*32 + u*16 + fr
  bf16x8 qf[2][4];
#pragma unroll
  for (int u = 0; u < 2; ++u) {
    int qrow = q0 + wv * 32 + u * 16 + fr;
#pragma unroll
    for (int ks = 0; ks < 4; ++ks)
      qf[u][ks] = *(const bf16x8*)(Qb + (size_t)qrow * HD + ks * 32 + fq * 8);
  }

  f32x4 zero4 = {0.f, 0.f, 0.f, 0.f};
  f32x4 o[2][8];
  float m[2][4], l[2][4];
#pragma unroll
  for (int u = 0; u < 2; ++u) {
#pragma unroll
    for (int dt = 0; dt < 8; ++dt) o[u][dt] = zero4;
#pragma unroll
    for (int r = 0; r < 4; ++r) { m[u][r] = -3.0e38f; l[u][r] = 0.f; }
  }

  const int ntiles = (q0 >> 6) + 2;
  for (int t = 0; t < ntiles; ++t) {
    const int s0 = t * 64;
    __syncthreads();
    // stage K (16 chunks) + V (16 chunks): linear LDS dest, swizzled source
#pragma unroll
    for (int j = 0; j < 4; ++j) {
      int c = j * 4 + wv;
      {
        int row = c * 4 + (lane >> 4);
        int e = ((lane & 15) ^ (row & 7)) * 8;
        gload16(Kb + (size_t)(s0 + row) * HD + e, sK + c * 512);
      }
      {
        int row = c * 8 + (lane >> 3);
        int e = ((lane & 7) ^ (row & 7)) * 8;
        gload16(Vb + (size_t)row * S_LEN + s0 + e, sV + c * 512);
      }
    }
    __syncthreads();

    // QK^T: sc[u][j] rows q=u*16+fq*4+r (C-layout), cols kv=s0+j*16+fr
    f32x4 sc[2][4];
#pragma unroll
    for (int u = 0; u < 2; ++u)
#pragma unroll
      for (int j = 0; j < 4; ++j) sc[u][j] = zero4;
#pragma unroll
    for (int j = 0; j < 4; ++j) {
#pragma unroll
      for (int ks = 0; ks < 4; ++ks) {
        int row = j * 16 + fr;
        int e = (ks * 32 + fq * 8) ^ ((row & 7) << 3);
        bf16x8 kf = *(const bf16x8*)(sK + row * 128 + e);
#pragma unroll
        for (int u = 0; u < 2; ++u)
          sc[u][j] = __builtin_amdgcn_mfma_f32_16x16x32_bf16(qf[u][ks], kf, sc[u][j], 0, 0, 0);
      }
    }

    if (t >= ntiles - 2) {  // diagonal tiles: causal mask
#pragma unroll
      for (int u = 0; u < 2; ++u)
#pragma unroll
        for (int j = 0; j < 4; ++j)
#pragma unroll
          for (int r = 0; r < 4; ++r) {
            int kvp = s0 + j * 16 + fr;
            int qp = q0 + wv * 32 + u * 16 + fq * 4 + r;
            if (kvp > qp) sc[u][j][r] = -3.0e38f;
          }
    }

    // online softmax (row groups: 16 lanes sharing fq)
#pragma unroll
    for (int u = 0; u < 2; ++u) {
      float al[4];
#pragma unroll
      for (int r = 0; r < 4; ++r) {
        float v = fmaxf(fmaxf(sc[u][0][r], sc[u][1][r]), fmaxf(sc[u][2][r], sc[u][3][r]));
        v = fmaxf(v, __shfl_xor(v, 1, 64));
        v = fmaxf(v, __shfl_xor(v, 2, 64));
        v = fmaxf(v, __shfl_xor(v, 4, 64));
        v = fmaxf(v, __shfl_xor(v, 8, 64));
        float mn = fmaxf(m[u][r], v);
        al[r] = __expf(m[u][r] - mn);
        m[u][r] = mn;
      }
#pragma unroll
      for (int r = 0; r < 4; ++r) {
        float rs = 0.f;
        int prow = u * 16 + fq * 4 + r;
#pragma unroll
        for (int j = 0; j < 4; ++j) {
          float p = __expf(sc[u][j][r] - m[u][r]);
          rs += p;
          int e = (j * 16 + fr) ^ ((prow & 7) << 3);
          sP[wv][prow * 64 + e] = f2bf(p);
        }
        rs += __shfl_xor(rs, 1, 64);
        rs += __shfl_xor(rs, 2, 64);
        rs += __shfl_xor(rs, 4, 64);
        rs += __shfl_xor(rs, 8, 64);
        l[u][r] = l[u][r] * al[r] + rs;
#pragma unroll
        for (int dt = 0; dt < 8; ++dt) o[u][dt][r] *= al[r];
      }
    }

    // P as A-fragments (same-wave LDS write->read): rows u*16+fr
    bf16x8 pa[2][2];
#pragma unroll
    for (int u = 0; u < 2; ++u)
#pragma unroll
      for (int ks = 0; ks < 2; ++ks) {
        int prow = u * 16 + fr;
        int e = (ks * 32 + fq * 8) ^ ((prow & 7) << 3);
        pa[u][ks] = *(const bf16x8*)(&sP[wv][prow * 64 + e]);
      }
    // PV: o[u][dt] rows q, cols d=dt*16+fr; each vf feeds both u-fragments
#pragma unroll
    for (int dt = 0; dt < 8; ++dt) {
#pragma unroll
      for (int ks = 0; ks < 2; ++ks) {
        int row = dt * 16 + fr;
        int e = (ks * 32 + fq * 8) ^ ((row & 7) << 3);
        bf16x8 vf = *(const bf16x8*)(sV + row * 64 + e);
#pragma unroll
        for (int u = 0; u < 2; ++u)
          o[u][dt] = __builtin_amdgcn_mfma_f32_16x16x32_bf16(pa[u][ks], vf, o[u][dt], 0, 0, 0);
      }
    }
  }

  // epilogue: out[(b*S+q)*4096 + h*128 + d]
#pragma unroll
  for (int u = 0; u < 2; ++u)
#pragma unroll
    for (int r = 0; r < 4; ++r) {
      int qp = q0 + wv * 32 + u * 16 + fq * 4 + r;
      float inv_l = 1.0f / l[u][r];
      size_t base = ((size_t)b * S_LEN + qp) * DM + h * HD;
#pragma unroll
      for (int dt = 0; dt < 8; ++dt)
        O[base + dt * 16 + fr] = f2bf(o[u][dt][r] * inv_l);
    }
}

extern "C" void kernel_launch(void* const* d_in, const int* in_sizes, int n_in,
                              void* d_out, int out_size, void* d_ws, size_t ws_size,
                              hipStream_t stream) {
  const float* x  = (const float*)d_in[0];
  const float* wq = (const float*)d_in[1];
  const float* wk = (const float*)d_in[2];
  const float* wv = (const float*)d_in[3];
  const float* wo = (const float*)d_in[4];

  char* ws = (char*)d_ws;
  size_t off = 0;
  auto alloc = [&](size_t bytes) {
    void* p = ws + off;
    off += (bytes + 255) & ~(size_t)255;
    return p;
  };

  const size_t nx  = (size_t)2 * S_LEN * DM;       // 16.78M elements
  const size_t nwq = (size_t)DM * DM;              // 16.78M
  const size_t nwk = (size_t)(NKVH * HD) * DM;     // 4.19M

  const float scale = 0.08838834764831845f;  // 1/sqrt(128), folded into Q
  const int nrq = 2 * NQH * S_LEN, nrk = 2 * NKVH * S_LEN;
  dim3 blk(256);

  if (ws_size >= ((size_t)180 << 20)) {
    // -------- fast path: one-time bf16 conversion + gload16 GEMMs --------
    u16* xb  = (u16*)alloc(nx * 2);   // also reused as aob after x dies
    u16* wqb = (u16*)alloc(nwq * 2);
    u16* wkb = (u16*)alloc(nwk * 2);
    u16* wvb = (u16*)alloc(nwk * 2);
    u16* wob = (u16*)alloc(nwq * 2);
    u16* qb  = (u16*)alloc(nx * 2);
    u16* kb  = (u16*)alloc(nwk * 2);
    u16* vtb = (u16*)alloc(nwk * 2);
    float* sin_t = (float*)alloc((size_t)S_LEN * 64 * 4);
    float* cos_t = (float*)alloc((size_t)S_LEN * 64 * 4);
    u16* aob = xb;  // alias: x (bf16) dead after the three projections

    auto cvt = [&](const float* in, u16* outb, size_t n) {
      int n8 = (int)(n / 8);
      cvt_f32_bf16<<<(n8 + 255) / 256, 256, 0, stream>>>(in, outb, n8);
    };
    cvt(x, xb, nx);
    cvt(wq, wqb, nwq);
    cvt(wk, wkb, nwk);
    cvt(wv, wvb, nwk);
    cvt(wo, wob, nwq);

    rope_table_kernel<<<(S_LEN * 64 + 255) / 256, 256, 0, stream>>>(sin_t, cos_t);

    gemm16<1, u16><<<dim3(32, 32), blk, 0, stream>>>(xb, wqb, qb, 4096, DM, DM, NQH);
    gemm16<1, u16><<<dim3(8, 32), blk, 0, stream>>>(xb, wkb, kb, 4096, 1024, DM, NKVH);
    gemm16<2, u16><<<dim3(8, 32), blk, 0, stream>>>(xb, wvb, vtb, 4096, 1024, DM, NKVH);

    rope_apply<<<((size_t)nrq * 64 + 255) / 256, 256, 0, stream>>>(qb, sin_t, cos_t, scale, nrq);
    rope_apply<<<((size_t)nrk * 64 + 255) / 256, 256, 0, stream>>>(kb, sin_t, cos_t, 1.0f, nrk);

    attn_kernel<<<dim3(16, 64), blk, 0, stream>>>(qb, kb, vtb, aob);

    gemm16<0, float><<<dim3(32, 32), blk, 0, stream>>>(aob, wob, (float*)d_out, 4096, DM, DM, 0);
  } else {
    // -------- fallback: proven round-10 path (f32 reg-staged GEMMs) --------
    u16* qb  = (u16*)alloc(nx * 2);
    u16* kb  = (u16*)alloc(nwk * 2);
    u16* vtb = (u16*)alloc(nwk * 2);
    u16* aob = (u16*)alloc(nx * 2);
    float* sin_t = (float*)alloc((size_t)S_LEN * 64 * 4);
    float* cos_t = (float*)alloc((size_t)S_LEN * 64 * 4);

    rope_table_kernel<<<(S_LEN * 64 + 255) / 256, 256, 0, stream>>>(sin_t, cos_t);

    gemm_bt<1, float, float, u16><<<dim3(32, 32), blk, 0, stream>>>(x, wq, qb, 4096, DM, DM, NQH);
    gemm_bt<1, float, float, u16><<<dim3(8, 32), blk, 0, stream>>>(x, wk, kb, 4096, 1024, DM, NKVH);
    gemm_bt<2, float, float, u16><<<dim3(8, 32), blk, 0, stream>>>(x, wv, vtb, 4096, 1024, DM, NKVH);

    rope_apply<<<((size_t)nrq * 64 + 255) / 256, 256, 0, stream>>>(qb, sin_t, cos_t, scale, nrq);
    rope_apply<<<((size_t)nrk * 64 + 255) / 256, 256, 0, stream>>>(kb, sin_t, cos_t, 1.0f, nrk);

    attn_kernel<<<dim3(16, 64), blk, 0, stream>>>(qb, kb, vtb, aob);

    gemm_bt<0, u16, float, float><<<dim3(32, 32), blk, 0, stream>>>(aob, wo, (float*)d_out, 4096, DM, DM, 0);
  }
}